// Round 5
// baseline (467.575 us; speedup 1.0000x reference)
//
#include <hip/hip_runtime.h>
#include <hip/hip_bf16.h>

#define FDIM 128
#define BROWS 25     // i1-window rows per bucket (<=32 for 5-bit loc pack)
#define NSUP 4       // i0 superbuckets (G slice ~3.2MB, fits XCD L2)
#define NCOL 64      // cursor colors per bucket (kills same-address atomic serialization)

// ---- bf16 helpers (manual, RNE) ----
static __device__ __forceinline__ unsigned short f2bf(float x) {
    unsigned u = __float_as_uint(x);
    unsigned r = 0x7fffu + ((u >> 16) & 1u);
    return (unsigned short)((u + r) >> 16);
}
static __device__ __forceinline__ float bf_lo(unsigned u) { return __uint_as_float(u << 16); }
static __device__ __forceinline__ float bf_hi(unsigned u) { return __uint_as_float(u & 0xffff0000u); }

// ---- k0: Ws = W + W^T ----
__global__ void make_ws(const float* __restrict__ W, float* __restrict__ Ws) {
    int idx = blockIdx.x * blockDim.x + threadIdx.x;
    int i = idx >> 7, j = idx & 127;
    Ws[idx] = W[i * FDIM + j] + W[j * FDIM + i];
}

// ---- k1: G = F @ Ws (bf16 out) AND Fbf = bf16(F) from the staged tile ----
__global__ __launch_bounds__(256, 2) void gemm_g(
    const float* __restrict__ Fm, const float* __restrict__ Ws,
    unsigned short* __restrict__ Gbf, unsigned short* __restrict__ Fbf, int N) {
    __shared__ float sWs[FDIM * FDIM];
    __shared__ float sF[32][FDIM];

    for (int k = threadIdx.x; k < FDIM * FDIM / 4; k += 256)
        ((float4*)sWs)[k] = ((const float4*)Ws)[k];

    int row0 = blockIdx.x * 32;
    for (int k = threadIdx.x; k < 32 * FDIM / 4; k += 256) {
        int r = k >> 5, c = k & 31;
        int gr = row0 + r;
        float4 v = make_float4(0.f, 0.f, 0.f, 0.f);
        if (gr < N) v = ((const float4*)Fm)[(size_t)gr * (FDIM / 4) + c];
        ((float4*)&sF[r][0])[c] = v;
    }
    __syncthreads();

    for (int k = threadIdx.x; k < 32 * FDIM / 4; k += 256) {
        int r = k >> 5, c = k & 31;
        int gr = row0 + r;
        if (gr < N) {
            float4 v = ((float4*)&sF[r][0])[c];
            ushort4 o;
            o.x = f2bf(v.x); o.y = f2bf(v.y); o.z = f2bf(v.z); o.w = f2bf(v.w);
            *(ushort4*)(Fbf + (size_t)gr * FDIM + c * 4) = o;
        }
    }

    int tx = threadIdx.x & 31;
    int ty = threadIdx.x >> 5;
    int c0 = tx * 4;
    float acc[4][4] = {};

    for (int i = 0; i < FDIM; ++i) {
        float4 w = *(const float4*)&sWs[i * FDIM + c0];
        float f0 = sF[ty * 4 + 0][i];
        float f1 = sF[ty * 4 + 1][i];
        float f2 = sF[ty * 4 + 2][i];
        float f3 = sF[ty * 4 + 3][i];
        acc[0][0] = fmaf(f0, w.x, acc[0][0]); acc[0][1] = fmaf(f0, w.y, acc[0][1]);
        acc[0][2] = fmaf(f0, w.z, acc[0][2]); acc[0][3] = fmaf(f0, w.w, acc[0][3]);
        acc[1][0] = fmaf(f1, w.x, acc[1][0]); acc[1][1] = fmaf(f1, w.y, acc[1][1]);
        acc[1][2] = fmaf(f1, w.z, acc[1][2]); acc[1][3] = fmaf(f1, w.w, acc[1][3]);
        acc[2][0] = fmaf(f2, w.x, acc[2][0]); acc[2][1] = fmaf(f2, w.y, acc[2][1]);
        acc[2][2] = fmaf(f2, w.z, acc[2][2]); acc[2][3] = fmaf(f2, w.w, acc[2][3]);
        acc[3][0] = fmaf(f3, w.x, acc[3][0]); acc[3][1] = fmaf(f3, w.y, acc[3][1]);
        acc[3][2] = fmaf(f3, w.z, acc[3][2]); acc[3][3] = fmaf(f3, w.w, acc[3][3]);
    }

    for (int r = 0; r < 4; ++r) {
        int gr = row0 + ty * 4 + r;
        if (gr < N) {
            ushort4 o;
            o.x = f2bf(acc[r][0]); o.y = f2bf(acc[r][1]);
            o.z = f2bf(acc[r][2]); o.w = f2bf(acc[r][3]);
            *(ushort4*)(Gbf + (size_t)gr * FDIM + c0) = o;
        }
    }
}

// ---- k2: histogram, one thread per edge, colored counters cnt[c*nb+b] ----
__global__ __launch_bounds__(256) void k_hist(const int* __restrict__ idx, int E,
                                              int supRows, int nI1, int nb,
                                              unsigned* __restrict__ cnt) {
    int e = blockIdx.x * 256 + threadIdx.x;
    if (e < E) {
        int i0 = idx[e];
        int i1 = idx[E + e];
        int b = (i0 / supRows) * nI1 + i1 / BROWS;
        atomicAdd(&cnt[(size_t)(blockIdx.x & (NCOL - 1)) * nb + b], 1u);
    }
}

// ---- k3a: per-bucket totals (coalesced across b) ----
__global__ __launch_bounds__(256) void k_btot(const unsigned* __restrict__ cnt, int nb,
                                              unsigned* __restrict__ tot) {
    int b = blockIdx.x * 256 + threadIdx.x;
    if (b < nb) {
        unsigned s = 0;
        for (int c = 0; c < NCOL; ++c) s += cnt[(size_t)c * nb + b];
        tot[b] = s;
    }
}

// ---- k3b: single-block exclusive scan of tot[0..nb) -> bucketStart ----
__global__ __launch_bounds__(256) void k_bscan(const unsigned* __restrict__ tot, int nb,
                                               unsigned* __restrict__ bucketStart) {
    __shared__ unsigned wS[4];
    int t = threadIdx.x;
    int per = (nb + 255) / 256;   // 32
    unsigned local[32];
    unsigned s = 0;
    for (int i = 0; i < per; ++i) {
        int b = t * per + i;
        unsigned v = (b < nb) ? tot[b] : 0u;
        local[i] = s;
        s += v;
    }
    int lane = t & 63, wid = t >> 6;
    unsigned incl = s;
    for (int d = 1; d < 64; d <<= 1) {
        unsigned u = __shfl_up(incl, d, 64);
        if (lane >= d) incl += u;
    }
    if (lane == 63) wS[wid] = incl;
    __syncthreads();
    unsigned wOff = 0;
    for (int i = 0; i < wid; ++i) wOff += wS[i];
    unsigned base = wOff + incl - s;
    for (int i = 0; i < per; ++i) {
        int b = t * per + i;
        if (b < nb) bucketStart[b] = base + local[i];
    }
    if (t == 255) bucketStart[nb] = base + s;
}

// ---- k3c: turn colored counts into colored cursors (in place) ----
__global__ __launch_bounds__(256) void k_ccur(unsigned* __restrict__ cnt, int nb,
                                              const unsigned* __restrict__ bucketStart) {
    int b = blockIdx.x * 256 + threadIdx.x;
    if (b < nb) {
        unsigned run = bucketStart[b];
        for (int c = 0; c < NCOL; ++c) {
            unsigned u = cnt[(size_t)c * nb + b];
            cnt[(size_t)c * nb + b] = run;
            run += u;
        }
    }
}

// ---- k4: scatter via colored atomic cursors ----
__global__ __launch_bounds__(256) void k_scatter(const int* __restrict__ idx,
                                                 const int* __restrict__ mol, int E,
                                                 int supRows, int nI1, int nb,
                                                 unsigned* __restrict__ cursor,
                                                 unsigned* __restrict__ sortedE) {
    int e = blockIdx.x * 256 + threadIdx.x;
    if (e < E) {
        int i0 = idx[e];
        int i1 = idx[E + e];
        int m  = mol[e];
        int i1b = i1 / BROWS;
        int b = (i0 / supRows) * nI1 + i1b;
        int loc = i1 - i1b * BROWS;
        unsigned pos = atomicAdd(&cursor[(size_t)(blockIdx.x & (NCOL - 1)) * nb + b], 1u);
        sortedE[pos] = (unsigned)i0 | ((unsigned)m << 16) | ((unsigned)loc << 26);
    }
}

// ---- k5: edge kernel, depth-2 register pipeline. One WG per bucket. ----
__global__ __launch_bounds__(256) void edge_kernel(
    const unsigned short* __restrict__ Gbf, const unsigned short* __restrict__ Fbf,
    const unsigned* __restrict__ sortedE, const unsigned* __restrict__ bucketStart,
    float* __restrict__ part, int nI1, int N) {
    __shared__ unsigned short sFrow[32 * FDIM];   // 8 KB

    int b = blockIdx.x;
    int i1b = b % nI1;
    int row0 = i1b * BROWS;
    int nrow = min(BROWS, N - row0);
    for (int k = threadIdx.x; k < nrow * (FDIM / 8); k += 256)
        ((uint4*)sFrow)[k] = ((const uint4*)(Fbf + (size_t)row0 * FDIM))[k];
    __syncthreads();

    const int s = bucketStart[b];
    const int e_end = bucketStart[b + 1];
    const int lane = threadIdx.x & 63;
    const int sub  = lane >> 4;
    const int t16  = lane & 15;
    const int off16 = t16 * 8;
    const int wid  = threadIdx.x >> 6;
    float* pout = part + ((b & 31) << 10);

    const int start = s + wid * 4;
    const int nIter = (e_end > start) ? ((e_end - start + 15) >> 4) : 0;

    unsigned pk[2] = {0u, 0u};
    uint4 g[2], f[2];

    // prologue
    if (nIter > 0) {
        int e0 = start + sub;
        pk[0] = (e0 < e_end) ? sortedE[e0] : 0u;
        g[0] = *(const uint4*)(Gbf + (size_t)(pk[0] & 0xffff) * FDIM + off16);
        f[0] = *(const uint4*)(sFrow + (pk[0] >> 26) * FDIM + off16);
    }
    if (nIter > 1) {
        int e1 = start + 16 + sub;
        pk[1] = (e1 < e_end) ? sortedE[e1] : 0u;
    }

    for (int it = 0; it < nIter; ++it) {
        const int cur = it & 1, nxt = cur ^ 1;
        // issue stage: pk for it+2, g/f for it+1
        unsigned pkN2 = 0u;
        if (it + 2 < nIter) {
            int e2 = start + (it + 2) * 16 + sub;
            pkN2 = (e2 < e_end) ? sortedE[e2] : 0u;
        }
        if (it + 1 < nIter) {
            g[nxt] = *(const uint4*)(Gbf + (size_t)(pk[nxt] & 0xffff) * FDIM + off16);
            f[nxt] = *(const uint4*)(sFrow + (pk[nxt] >> 26) * FDIM + off16);
        }
        // consume stage
        const unsigned p0 = pk[cur];
        const uint4 gg = g[cur];
        const uint4 ff = f[cur];
        float p;
        p = bf_lo(gg.x) * bf_lo(ff.x);
        p = fmaf(bf_hi(gg.x), bf_hi(ff.x), p);
        p = fmaf(bf_lo(gg.y), bf_lo(ff.y), p);
        p = fmaf(bf_hi(gg.y), bf_hi(ff.y), p);
        p = fmaf(bf_lo(gg.z), bf_lo(ff.z), p);
        p = fmaf(bf_hi(gg.z), bf_hi(ff.z), p);
        p = fmaf(bf_lo(gg.w), bf_lo(ff.w), p);
        p = fmaf(bf_hi(gg.w), bf_hi(ff.w), p);
        const int e = start + it * 16 + sub;
        if (e >= e_end) p = 0.f;
        p += __shfl_xor(p, 1, 16);
        p += __shfl_xor(p, 2, 16);
        p += __shfl_xor(p, 4, 16);
        p += __shfl_xor(p, 8, 16);
        if (t16 == 0 && e < e_end) atomicAdd(pout + ((p0 >> 16) & 0x3ff), p);
        pk[cur] = pkN2;
    }
}

// ---- k6: reduce 32 partial copies -> out ----
__global__ __launch_bounds__(256) void k_red(const float* __restrict__ part,
                                             float* __restrict__ out, int M) {
    int m = blockIdx.x * 256 + threadIdx.x;
    if (m < M) {
        float s = 0.f;
        for (int c = 0; c < 32; ++c) s += part[(c << 10) + m];
        out[m] = s;
    }
}

extern "C" void kernel_launch(void* const* d_in, const int* in_sizes, int n_in,
                              void* d_out, int out_size, void* d_ws, size_t ws_size,
                              hipStream_t stream) {
    const float* Fm = (const float*)d_in[0];
    const float* W  = (const float*)d_in[1];
    const int* idx  = (const int*)d_in[2];
    const int* mol  = (const int*)d_in[3];
    float* out = (float*)d_out;

    const int N = in_sizes[0] / FDIM;   // 50000
    const int E = in_sizes[3];          // 1600000

    const int nI1     = (N + BROWS - 1) / BROWS;    // 2000
    const int supRows = (N + NSUP - 1) / NSUP;      // 12500
    const int nb      = NSUP * nI1;                 // 8000

    // workspace layout
    char* ws = (char*)d_ws;
    size_t o = 0;
    float* Ws = (float*)(ws + o);                    o += 64 * 1024;
    unsigned short* Fbf = (unsigned short*)(ws + o); o += ((size_t)N * FDIM * 2 + 255) & ~(size_t)255;
    unsigned short* Gbf = (unsigned short*)(ws + o); o += ((size_t)N * FDIM * 2 + 255) & ~(size_t)255;
    unsigned* sortedE = (unsigned*)(ws + o);         o += ((size_t)E * 4 + 255) & ~(size_t)255;
    unsigned* cnt = (unsigned*)(ws + o);             o += (size_t)NCOL * nb * 4;
    unsigned* tot = (unsigned*)(ws + o);             o += ((size_t)nb * 4 + 255) & ~(size_t)255;
    unsigned* bucketStart = (unsigned*)(ws + o);     o += ((size_t)(nb + 1) * 4 + 255) & ~(size_t)255;
    float* part = (float*)(ws + o);                  o += 32 * 1024 * sizeof(float);

    hipMemsetAsync(cnt, 0, (size_t)NCOL * nb * 4, stream);
    hipMemsetAsync(part, 0, 32 * 1024 * sizeof(float), stream);

    make_ws<<<FDIM * FDIM / 256, 256, 0, stream>>>(W, Ws);
    gemm_g<<<(N + 31) / 32, 256, 0, stream>>>(Fm, Ws, Gbf, Fbf, N);

    int eBlocks = (E + 255) / 256;
    k_hist<<<eBlocks, 256, 0, stream>>>(idx, E, supRows, nI1, nb, cnt);
    k_btot<<<(nb + 255) / 256, 256, 0, stream>>>(cnt, nb, tot);
    k_bscan<<<1, 256, 0, stream>>>(tot, nb, bucketStart);
    k_ccur<<<(nb + 255) / 256, 256, 0, stream>>>(cnt, nb, bucketStart);
    k_scatter<<<eBlocks, 256, 0, stream>>>(idx, mol, E, supRows, nI1, nb, cnt, sortedE);

    edge_kernel<<<nb, 256, 0, stream>>>(Gbf, Fbf, sortedE, bucketStart, part, nI1, N);

    k_red<<<(out_size + 255) / 256, 256, 0, stream>>>(part, out, out_size);
}

// Round 6
// 285.283 us; speedup vs baseline: 1.6390x; 1.6390x over previous
//
#include <hip/hip_runtime.h>
#include <hip/hip_bf16.h>

#define FDIM 128
#define BROWS 32     // i1 rows per bucket: bin = i1>>5, loc = i1&31 (5-bit pack)
#define NBLK 256     // partition blocks for hist/scatter

// ---- bf16 helpers (manual, RNE) ----
static __device__ __forceinline__ unsigned short f2bf(float x) {
    unsigned u = __float_as_uint(x);
    unsigned r = 0x7fffu + ((u >> 16) & 1u);
    return (unsigned short)((u + r) >> 16);
}
static __device__ __forceinline__ float bf_lo(unsigned u) { return __uint_as_float(u << 16); }
static __device__ __forceinline__ float bf_hi(unsigned u) { return __uint_as_float(u & 0xffff0000u); }

// ---- k0: Ws = W + W^T ----
__global__ void make_ws(const float* __restrict__ W, float* __restrict__ Ws) {
    int idx = blockIdx.x * blockDim.x + threadIdx.x;
    int i = idx >> 7, j = idx & 127;
    Ws[idx] = W[i * FDIM + j] + W[j * FDIM + i];
}

// ---- k1: G = F @ Ws (bf16 out) ----
__global__ __launch_bounds__(256, 2) void gemm_g(
    const float* __restrict__ Fm, const float* __restrict__ Ws,
    unsigned short* __restrict__ Gbf, int N) {
    __shared__ float sWs[FDIM * FDIM];
    __shared__ float sF[32][FDIM];

    for (int k = threadIdx.x; k < FDIM * FDIM / 4; k += 256)
        ((float4*)sWs)[k] = ((const float4*)Ws)[k];

    int row0 = blockIdx.x * 32;
    for (int k = threadIdx.x; k < 32 * FDIM / 4; k += 256) {
        int r = k >> 5, c = k & 31;
        int gr = row0 + r;
        float4 v = make_float4(0.f, 0.f, 0.f, 0.f);
        if (gr < N) v = ((const float4*)Fm)[(size_t)gr * (FDIM / 4) + c];
        ((float4*)&sF[r][0])[c] = v;
    }
    __syncthreads();

    int tx = threadIdx.x & 31;
    int ty = threadIdx.x >> 5;
    int c0 = tx * 4;
    float acc[4][4] = {};

    for (int i = 0; i < FDIM; ++i) {
        float4 w = *(const float4*)&sWs[i * FDIM + c0];
        float f0 = sF[ty * 4 + 0][i];
        float f1 = sF[ty * 4 + 1][i];
        float f2 = sF[ty * 4 + 2][i];
        float f3 = sF[ty * 4 + 3][i];
        acc[0][0] = fmaf(f0, w.x, acc[0][0]); acc[0][1] = fmaf(f0, w.y, acc[0][1]);
        acc[0][2] = fmaf(f0, w.z, acc[0][2]); acc[0][3] = fmaf(f0, w.w, acc[0][3]);
        acc[1][0] = fmaf(f1, w.x, acc[1][0]); acc[1][1] = fmaf(f1, w.y, acc[1][1]);
        acc[1][2] = fmaf(f1, w.z, acc[1][2]); acc[1][3] = fmaf(f1, w.w, acc[1][3]);
        acc[2][0] = fmaf(f2, w.x, acc[2][0]); acc[2][1] = fmaf(f2, w.y, acc[2][1]);
        acc[2][2] = fmaf(f2, w.z, acc[2][2]); acc[2][3] = fmaf(f2, w.w, acc[2][3]);
        acc[3][0] = fmaf(f3, w.x, acc[3][0]); acc[3][1] = fmaf(f3, w.y, acc[3][1]);
        acc[3][2] = fmaf(f3, w.z, acc[3][2]); acc[3][3] = fmaf(f3, w.w, acc[3][3]);
    }

    for (int r = 0; r < 4; ++r) {
        int gr = row0 + ty * 4 + r;
        if (gr < N) {
            ushort4 o;
            o.x = f2bf(acc[r][0]); o.y = f2bf(acc[r][1]);
            o.z = f2bf(acc[r][2]); o.w = f2bf(acc[r][3]);
            *(ushort4*)(Gbf + (size_t)gr * FDIM + c0) = o;
        }
    }
}

// ---- k2: LDS histogram per partition block -> M[k][b] (coalesced dump) ----
__global__ __launch_bounds__(256) void k_hist(const int* __restrict__ idx, int E,
                                              int nb, unsigned* __restrict__ M) {
    extern __shared__ unsigned cnt[];
    for (int i = threadIdx.x; i < nb; i += 256) cnt[i] = 0;
    __syncthreads();
    int chunk = (E + NBLK - 1) / NBLK;
    int s = blockIdx.x * chunk;
    int e_end = min(E, s + chunk);
    for (int e = s + threadIdx.x; e < e_end; e += 256) {
        int i1 = idx[E + e];
        atomicAdd(&cnt[i1 >> 5], 1u);
    }
    __syncthreads();
    for (int i = threadIdx.x; i < nb; i += 256)
        M[(size_t)blockIdx.x * nb + i] = cnt[i];
}

// ---- k3a: per-bucket totals, tot[b] = sum_k M[k][b] (x8 unrolled, coalesced) ----
__global__ __launch_bounds__(256) void k_btot(const unsigned* __restrict__ M, int nb,
                                              unsigned* __restrict__ tot) {
    int b = blockIdx.x * 256 + threadIdx.x;
    if (b < nb) {
        unsigned s = 0;
        for (int k = 0; k < NBLK; k += 8) {
            unsigned t0 = M[(size_t)(k + 0) * nb + b];
            unsigned t1 = M[(size_t)(k + 1) * nb + b];
            unsigned t2 = M[(size_t)(k + 2) * nb + b];
            unsigned t3 = M[(size_t)(k + 3) * nb + b];
            unsigned t4 = M[(size_t)(k + 4) * nb + b];
            unsigned t5 = M[(size_t)(k + 5) * nb + b];
            unsigned t6 = M[(size_t)(k + 6) * nb + b];
            unsigned t7 = M[(size_t)(k + 7) * nb + b];
            s += t0 + t1 + t2 + t3 + t4 + t5 + t6 + t7;
        }
        tot[b] = s;
    }
}

// ---- k3b: single-block exclusive scan of tot -> bucketStart (8/thread, unrolled) ----
__global__ __launch_bounds__(256) void k_bscan(const unsigned* __restrict__ tot, int nb,
                                               unsigned* __restrict__ bucketStart) {
    __shared__ unsigned wS[4];
    int t = threadIdx.x;
    unsigned v0, v1, v2, v3, v4, v5, v6, v7;
    int b0 = t * 8;
    v0 = (b0 + 0 < nb) ? tot[b0 + 0] : 0u;
    v1 = (b0 + 1 < nb) ? tot[b0 + 1] : 0u;
    v2 = (b0 + 2 < nb) ? tot[b0 + 2] : 0u;
    v3 = (b0 + 3 < nb) ? tot[b0 + 3] : 0u;
    v4 = (b0 + 4 < nb) ? tot[b0 + 4] : 0u;
    v5 = (b0 + 5 < nb) ? tot[b0 + 5] : 0u;
    v6 = (b0 + 6 < nb) ? tot[b0 + 6] : 0u;
    v7 = (b0 + 7 < nb) ? tot[b0 + 7] : 0u;
    unsigned l0 = 0, l1 = v0, l2 = l1 + v1, l3 = l2 + v2, l4 = l3 + v3,
             l5 = l4 + v4, l6 = l5 + v5, l7 = l6 + v6;
    unsigned s = l7 + v7;
    int lane = t & 63, wid = t >> 6;
    unsigned incl = s;
    for (int d = 1; d < 64; d <<= 1) {
        unsigned u = __shfl_up(incl, d, 64);
        if (lane >= d) incl += u;
    }
    if (lane == 63) wS[wid] = incl;
    __syncthreads();
    unsigned wOff = 0;
    for (int i = 0; i < wid; ++i) wOff += wS[i];
    unsigned base = wOff + incl - s;
    if (b0 + 0 < nb) bucketStart[b0 + 0] = base + l0;
    if (b0 + 1 < nb) bucketStart[b0 + 1] = base + l1;
    if (b0 + 2 < nb) bucketStart[b0 + 2] = base + l2;
    if (b0 + 3 < nb) bucketStart[b0 + 3] = base + l3;
    if (b0 + 4 < nb) bucketStart[b0 + 4] = base + l4;
    if (b0 + 5 < nb) bucketStart[b0 + 5] = base + l5;
    if (b0 + 6 < nb) bucketStart[b0 + 6] = base + l6;
    if (b0 + 7 < nb) bucketStart[b0 + 7] = base + l7;
    if (t == 255) bucketStart[nb] = base + s;
}

// ---- k3c: per-bucket running prefix over k: M[k][b] -> cursor start (x8 unrolled) ----
__global__ __launch_bounds__(256) void k_mscan(unsigned* __restrict__ M, int nb,
                                               const unsigned* __restrict__ bucketStart) {
    int b = blockIdx.x * 256 + threadIdx.x;
    if (b < nb) {
        unsigned run = bucketStart[b];
        for (int k = 0; k < NBLK; k += 8) {
            unsigned t0 = M[(size_t)(k + 0) * nb + b];
            unsigned t1 = M[(size_t)(k + 1) * nb + b];
            unsigned t2 = M[(size_t)(k + 2) * nb + b];
            unsigned t3 = M[(size_t)(k + 3) * nb + b];
            unsigned t4 = M[(size_t)(k + 4) * nb + b];
            unsigned t5 = M[(size_t)(k + 5) * nb + b];
            unsigned t6 = M[(size_t)(k + 6) * nb + b];
            unsigned t7 = M[(size_t)(k + 7) * nb + b];
            M[(size_t)(k + 0) * nb + b] = run; run += t0;
            M[(size_t)(k + 1) * nb + b] = run; run += t1;
            M[(size_t)(k + 2) * nb + b] = run; run += t2;
            M[(size_t)(k + 3) * nb + b] = run; run += t3;
            M[(size_t)(k + 4) * nb + b] = run; run += t4;
            M[(size_t)(k + 5) * nb + b] = run; run += t5;
            M[(size_t)(k + 6) * nb + b] = run; run += t6;
            M[(size_t)(k + 7) * nb + b] = run; run += t7;
        }
    }
}

// ---- k4: scatter via LDS cursors (no global atomics) ----
__global__ __launch_bounds__(256) void k_scatter(const int* __restrict__ idx,
                                                 const int* __restrict__ mol, int E,
                                                 int nb, const unsigned* __restrict__ M,
                                                 unsigned* __restrict__ sortedE) {
    extern __shared__ unsigned cur[];
    for (int i = threadIdx.x; i < nb; i += 256)
        cur[i] = M[(size_t)blockIdx.x * nb + i];
    __syncthreads();
    int chunk = (E + NBLK - 1) / NBLK;
    int s = blockIdx.x * chunk;
    int e_end = min(E, s + chunk);
    for (int e = s + threadIdx.x; e < e_end; e += 256) {
        int i0 = idx[e];
        int i1 = idx[E + e];
        int m  = mol[e];
        int b  = i1 >> 5;
        int loc = i1 & 31;
        unsigned pos = atomicAdd(&cur[b], 1u);
        sortedE[pos] = (unsigned)i0 | ((unsigned)m << 16) | ((unsigned)loc << 26);
    }
}

// ---- k5: edge kernel. One WG per bucket: F window (fp32->bf16) in LDS,
// gather G, accumulate per-molecule in LDS smol, flush with plain stores. ----
__global__ __launch_bounds__(256) void edge_kernel(
    const unsigned short* __restrict__ Gbf, const float* __restrict__ Fm,
    const unsigned* __restrict__ sortedE, const unsigned* __restrict__ bucketStart,
    float* __restrict__ part, int N, int Mout) {
    __shared__ unsigned short sFrow[BROWS * FDIM];   // 8 KB
    __shared__ float smol[1024];                     // 4 KB

    int b = blockIdx.x;
    int row0 = b * BROWS;
    int nrow = min(BROWS, N - row0);
    for (int k = threadIdx.x; k < nrow * (FDIM / 4); k += 256) {
        int r = k >> 5, c = k & 31;             // c indexes float4 within row
        float4 v = ((const float4*)(Fm + (size_t)(row0 + r) * FDIM))[c];
        ushort4 o;
        o.x = f2bf(v.x); o.y = f2bf(v.y); o.z = f2bf(v.z); o.w = f2bf(v.w);
        *(ushort4*)(sFrow + r * FDIM + c * 4) = o;
    }
    for (int i = threadIdx.x; i < 1024; i += 256) smol[i] = 0.f;
    __syncthreads();

    const int s = bucketStart[b];
    const int e_end = bucketStart[b + 1];
    const int lane = threadIdx.x & 63;
    const int sub  = lane >> 4;
    const int t16  = lane & 15;
    const int off16 = t16 * 8;
    const int wid  = threadIdx.x >> 6;

    for (int base = s + wid * 4; base < e_end; base += 16) {
        int e = base + sub;
        bool valid = (e < e_end);
        unsigned pk = valid ? sortedE[e] : 0u;
        int i0  = pk & 0xffff;
        int m   = (pk >> 16) & 0x3ff;
        int loc = pk >> 26;
        const uint4 g = *(const uint4*)(Gbf + (size_t)i0 * FDIM + off16);
        const uint4 f = *(const uint4*)(sFrow + loc * FDIM + off16);
        float p;
        p = bf_lo(g.x) * bf_lo(f.x);
        p = fmaf(bf_hi(g.x), bf_hi(f.x), p);
        p = fmaf(bf_lo(g.y), bf_lo(f.y), p);
        p = fmaf(bf_hi(g.y), bf_hi(f.y), p);
        p = fmaf(bf_lo(g.z), bf_lo(f.z), p);
        p = fmaf(bf_hi(g.z), bf_hi(f.z), p);
        p = fmaf(bf_lo(g.w), bf_lo(f.w), p);
        p = fmaf(bf_hi(g.w), bf_hi(f.w), p);
        p += __shfl_xor(p, 1, 16);
        p += __shfl_xor(p, 2, 16);
        p += __shfl_xor(p, 4, 16);
        p += __shfl_xor(p, 8, 16);
        if (t16 == 0 && valid) atomicAdd(&smol[m], p);
    }
    __syncthreads();
    float* prow = part + (size_t)b * 1024;
    for (int i = threadIdx.x; i < Mout; i += 256) prow[i] = smol[i];
}

// ---- k6a: partial reduce over buckets (8 slices) ----
__global__ __launch_bounds__(256) void k_red1(const float* __restrict__ part, int nb,
                                              float* __restrict__ partial, int Mout) {
    int gid = blockIdx.x * 256 + threadIdx.x;     // 8192 threads
    int m = gid & 1023;
    int sl = gid >> 10;                           // 0..7
    int per = (nb + 7) / 8;
    int b0 = sl * per;
    int b1 = min(nb, b0 + per);
    float s = 0.f;
    if (m < Mout) {
        for (int b = b0; b < b1; ++b) s += part[(size_t)b * 1024 + m];
    }
    partial[sl * 1024 + m] = s;
}

// ---- k6b: final reduce ----
__global__ __launch_bounds__(256) void k_red2(const float* __restrict__ partial,
                                              float* __restrict__ out, int Mout) {
    int m = blockIdx.x * 256 + threadIdx.x;
    if (m < Mout) {
        float s = 0.f;
        for (int sl = 0; sl < 8; ++sl) s += partial[sl * 1024 + m];
        out[m] = s;
    }
}

extern "C" void kernel_launch(void* const* d_in, const int* in_sizes, int n_in,
                              void* d_out, int out_size, void* d_ws, size_t ws_size,
                              hipStream_t stream) {
    const float* Fm = (const float*)d_in[0];
    const float* W  = (const float*)d_in[1];
    const int* idx  = (const int*)d_in[2];
    const int* mol  = (const int*)d_in[3];
    float* out = (float*)d_out;

    const int N = in_sizes[0] / FDIM;   // 50000
    const int E = in_sizes[3];          // 1600000

    const int nb = (N + BROWS - 1) / BROWS;   // 1563 buckets

    // workspace layout (~27 MB)
    char* ws = (char*)d_ws;
    size_t o = 0;
    float* Ws = (float*)(ws + o);                    o += 64 * 1024;
    unsigned short* Gbf = (unsigned short*)(ws + o); o += ((size_t)N * FDIM * 2 + 255) & ~(size_t)255;
    unsigned* sortedE = (unsigned*)(ws + o);         o += ((size_t)E * 4 + 255) & ~(size_t)255;
    unsigned* M = (unsigned*)(ws + o);               o += ((size_t)NBLK * nb * 4 + 255) & ~(size_t)255;
    unsigned* tot = (unsigned*)(ws + o);             o += ((size_t)nb * 4 + 255) & ~(size_t)255;
    unsigned* bucketStart = (unsigned*)(ws + o);     o += ((size_t)(nb + 1) * 4 + 255) & ~(size_t)255;
    float* part = (float*)(ws + o);                  o += (size_t)nb * 1024 * sizeof(float);
    float* partial = (float*)(ws + o);               o += 8 * 1024 * sizeof(float);

    make_ws<<<FDIM * FDIM / 256, 256, 0, stream>>>(W, Ws);
    gemm_g<<<(N + 31) / 32, 256, 0, stream>>>(Fm, Ws, Gbf, N);

    size_t smem = (size_t)nb * 4;
    k_hist<<<NBLK, 256, smem, stream>>>(idx, E, nb, M);
    k_btot<<<(nb + 255) / 256, 256, 0, stream>>>(M, nb, tot);
    k_bscan<<<1, 256, 0, stream>>>(tot, nb, bucketStart);
    k_mscan<<<(nb + 255) / 256, 256, 0, stream>>>(M, nb, bucketStart);
    k_scatter<<<NBLK, 256, smem, stream>>>(idx, mol, E, nb, M, sortedE);

    edge_kernel<<<nb, 256, 0, stream>>>(Gbf, Fm, sortedE, bucketStart, part, N, out_size);

    k_red1<<<32, 256, 0, stream>>>(part, nb, partial, out_size);
    k_red2<<<(out_size + 255) / 256, 256, 0, stream>>>(partial, out, out_size);
}